// Round 1
// baseline (261.931 us; speedup 1.0000x reference)
//
#include <hip/hip_runtime.h>

// LSTM RNN: B=2048, L=256 (257 scan steps), F=64, H=32, K=2.
// One wg = 8 batch rows, 4 waves. MFMA 16x16x32 bf16, K-extended to 128:
//   A = [h(64) | tanhv(32) | onehot(s_pad),1,pad]   (rows 8..15 duplicate 0..7)
//   B = [Wh; W_g2@Wi; W_emb@Wi; (b_emb+b_g2)@Wi + b_lstm]  (in VGPRs, static)
// N = 256 gate cols (+ 2 logit cols on wave 0). Gate math in-register,
// only h round-trips LDS (1KB double buffer, one barrier/step).

typedef __attribute__((ext_vector_type(8))) short bf16x8;
typedef __attribute__((ext_vector_type(4))) float f32x4;

#define L2E 1.44269504088896340736f
#define LN2 0.69314718055994530942f

__device__ __forceinline__ short f2bf(float x) {
    unsigned u = __builtin_bit_cast(unsigned, x);
    unsigned r = (u + 0x7FFFu + ((u >> 16) & 1u)) >> 16;
    return (short)r;
}
__device__ __forceinline__ float fsig(float x) {
    float e = __builtin_amdgcn_exp2f(-L2E * x);
    return __builtin_amdgcn_rcpf(1.0f + e);
}
__device__ __forceinline__ float ftanh(float x) {
    float e = __builtin_amdgcn_exp2f(-2.0f * L2E * x);
    return 2.0f * __builtin_amdgcn_rcpf(1.0f + e) - 1.0f;
}

__global__ __launch_bounds__(256) void lstm_kernel(
    const int* __restrict__ s, const float* __restrict__ g,
    const float* __restrict__ W_emb, const float* __restrict__ b_emb,
    const float* __restrict__ W_g1, const float* __restrict__ b_g1,
    const float* __restrict__ W_g2, const float* __restrict__ b_g2,
    const float* __restrict__ W_gh, const float* __restrict__ b_gh,
    const float* __restrict__ W_gc, const float* __restrict__ b_gc,
    const float* __restrict__ Wi, const float* __restrict__ Wh,
    const float* __restrict__ b_lstm, const float* __restrict__ W_amp,
    const float* __restrict__ b_amp, float* __restrict__ out)
{
    __shared__ float Bx[35 * 256];                 // rows 0-31: W_g2@Wi; 32-33: W_emb@Wi; 34: const
    __shared__ __align__(8) unsigned char s_l[2080]; // s_pad: [t][b], t=0..256, b=0..7
    __shared__ __align__(16) short Hb[2][512];     // h double buffer: [fgrp(8)][b(8)][8 bf16]

    const int tid = threadIdx.x;
    const int w   = tid >> 6;      // wave 0..3
    const int l   = tid & 63;      // lane
    const int wgb = blockIdx.x * 8;

    // ---------- Setup: compute folded B rows into LDS ----------
    {
        const int n = tid;  // 256 threads <-> 256 cols
        float acc[35];
        #pragma unroll
        for (int i = 0; i < 35; ++i) acc[i] = 0.f;
        for (int f = 0; f < 64; ++f) {
            float wi = Wi[f * 256 + n];
            #pragma unroll
            for (int k = 0; k < 32; ++k) acc[k] += W_g2[k * 64 + f] * wi;  // uniform loads
            acc[32] += W_emb[f] * wi;
            acc[33] += W_emb[64 + f] * wi;
            acc[34] += (b_emb[f] + b_g2[f]) * wi;
        }
        acc[34] += b_lstm[n];
        #pragma unroll
        for (int i = 0; i < 35; ++i) Bx[i * 256 + n] = acc[i];
    }
    // stage s_pad bytes: s_l[(t+1)*8+b] = s[b][t], s_l[0..7] = 0
    {
        const int b  = tid >> 5;
        const int t0 = (tid & 31) * 8;
        #pragma unroll
        for (int i = 0; i < 8; ++i) {
            int t = t0 + i;
            s_l[(t + 1) * 8 + b] = (unsigned char)s[(wgb + b) * 256 + t];
        }
        if (tid < 8) s_l[tid] = 0;
    }
    __syncthreads();

    // ---------- B fragments (registers, static over steps) ----------
    // B layout 16x16x32: lane holds B[k][n], n=lane&15, k=(lane>>4)*8+j
    bf16x8 Bf[4][4];
    #pragma unroll
    for (int gi = 0; gi < 4; ++gi) {
        const int n = gi * 64 + w * 16 + (l & 15);
        #pragma unroll
        for (int kf = 0; kf < 2; ++kf)
            #pragma unroll
            for (int j = 0; j < 8; ++j)
                Bf[gi][kf][j] = f2bf(Wh[(kf * 32 + (l >> 4) * 8 + j) * 256 + n]);
        #pragma unroll
        for (int j = 0; j < 8; ++j) {
            int kl = (l >> 4) * 8 + j;
            Bf[gi][2][j] = f2bf(Bx[kl * 256 + n]);
            float v3 = (kl < 2) ? Bx[(32 + kl) * 256 + n]
                                : ((kl == 2) ? Bx[34 * 256 + n] : 0.f);
            Bf[gi][3][j] = f2bf(v3);
        }
    }
    // logits tile (cols 256-257), used by wave 0 only
    bf16x8 BL0, BL1, BL3;
    {
        const int n2 = l & 15;
        #pragma unroll
        for (int j = 0; j < 8; ++j) {
            int k0 = (l >> 4) * 8 + j;
            BL0[j] = (n2 < 2) ? f2bf(W_amp[k0 * 2 + n2]) : (short)0;
            BL1[j] = (n2 < 2) ? f2bf(W_amp[(32 + k0) * 2 + n2]) : (short)0;
            BL3[j] = (k0 == 2 && n2 < 2) ? f2bf(b_amp[n2]) : (short)0;
        }
    }

    // ---------- A static fragment (tanhv) + per-lane state init ----------
    const int ba = l & 7;                 // A-side batch row (m>=8 duplicates m-8)
    const float g_a = g[wgb + ba];
    bf16x8 Atv;
    #pragma unroll
    for (int j = 0; j < 8; ++j) {
        int kl = (l >> 4) * 8 + j;
        Atv[j] = f2bf(tanhf(g_a * W_g1[kl] + b_g1[kl]));
    }

    // gate-phase ownership: lane l slot j owns (b, f):
    //   b = ((l&31)>>4)*4 + (l>>5)*2 + j  in [0,8),  f = w*16 + (l&15)
    const int fcol = w * 16 + (l & 15);
    float cst[2];
    int haddr[2];
    #pragma unroll
    for (int j = 0; j < 2; ++j) {
        int b = (((l & 31) >> 4) << 2) + ((l >> 5) << 1) + j;
        float gb = g[wgb + b];
        cst[j] = gb * W_gc[fcol] + b_gc[fcol];               // c0
        float h0 = gb * W_gh[fcol] + b_gh[fcol];             // h0
        int idx = ((fcol >> 3) << 6) + (b << 3) + (fcol & 7);
        haddr[j] = idx;
        Hb[0][idx] = f2bf(h0);
    }
    __syncthreads();

    // ---------- main recurrence: t = 0..256 ----------
    const int afidx0 = ((l >> 4) << 6) + (ba << 3);  // frag0 read idx; frag1 = +256
    const f32x4 zero4 = {0.f, 0.f, 0.f, 0.f};
    f32x4 accL = zero4;
    float slp[4] = {0.f, 0.f, 0.f, 0.f};

    for (int t = 0; t < 257; ++t) {
        const int rb = t & 1;
        bf16x8 a0 = *(const bf16x8*)&Hb[rb][afidx0];
        bf16x8 a1 = *(const bf16x8*)&Hb[rb][afidx0 + 256];

        // frag3: [1-s, s, 1, 0...] on k-local 0..2 (lane group 0 only)
        unsigned sv = s_l[t * 8 + ba];
        bf16x8 a3 = {0, 0, 0, 0, 0, 0, 0, 0};
        if ((l >> 4) == 0) {
            a3[0] = sv ? (short)0 : (short)0x3F80;
            a3[1] = sv ? (short)0x3F80 : (short)0;
            a3[2] = (short)0x3F80;
        }

        f32x4 acc[4];
        #pragma unroll
        for (int gi = 0; gi < 4; ++gi) {
            f32x4 a = __builtin_amdgcn_mfma_f32_16x16x32_bf16(a0, Bf[gi][0], zero4, 0, 0, 0);
            a = __builtin_amdgcn_mfma_f32_16x16x32_bf16(a1, Bf[gi][1], a, 0, 0, 0);
            a = __builtin_amdgcn_mfma_f32_16x16x32_bf16(Atv, Bf[gi][2], a, 0, 0, 0);
            acc[gi] = __builtin_amdgcn_mfma_f32_16x16x32_bf16(a3, Bf[gi][3], a, 0, 0, 0);
        }

        if (w == 0) {
            f32x4 aL = __builtin_amdgcn_mfma_f32_16x16x32_bf16(a0, BL0, zero4, 0, 0, 0);
            aL = __builtin_amdgcn_mfma_f32_16x16x32_bf16(a1, BL1, aL, 0, 0, 0);
            accL = __builtin_amdgcn_mfma_f32_16x16x32_bf16(a3, BL3, aL, 0, 0, 0);
            if (t >= 1) {
                // logits_{t-1} vs token s[t-1] = s_l[t]; rows b = ((l>>4)&1)*4 + r
                unsigned s4 = *(const unsigned*)&s_l[t * 8 + (((l >> 4) & 1) << 2)];
                #pragma unroll
                for (int r = 0; r < 4; ++r) {
                    float l0 = accL[r];
                    float l1 = __shfl_xor(l0, 1);
                    unsigned sr = (s4 >> (8 * r)) & 1u;
                    float x = sr ? (l0 - l1) : (l1 - l0);   // l_other - l_s
                    float e = __builtin_amdgcn_exp2f(L2E * x);
                    slp[r] -= LN2 * __builtin_amdgcn_logf(1.0f + e);
                }
            }
        }

        if (t < 256) {
            const int wb = 1 - rb;
            #pragma unroll
            for (int j = 0; j < 2; ++j) {
                // duplicated M rows make the needed acc element local: r = j (l<32) or j+2
                float zi = (l < 32) ? acc[0][j] : acc[0][j + 2];
                float zf = (l < 32) ? acc[1][j] : acc[1][j + 2];
                float zg = (l < 32) ? acc[2][j] : acc[2][j + 2];
                float zo = (l < 32) ? acc[3][j] : acc[3][j + 2];
                float si = fsig(zi), sf = fsig(zf), so = fsig(zo);
                float c = sf * cst[j] + si * ftanh(zg);
                cst[j] = c;
                float h = so * ftanh(c);
                Hb[wb][haddr[j]] = f2bf(h);
            }
        }
        __syncthreads();
    }

    // ---------- epilogue: store per-batch sums ----------
    if (w == 0 && (l & 15) == 0 && l < 32) {
        #pragma unroll
        for (int r = 0; r < 4; ++r)
            out[wgb + ((l >> 4) << 2) + r] = slp[r];
    }
}

extern "C" void kernel_launch(void* const* d_in, const int* in_sizes, int n_in,
                              void* d_out, int out_size, void* d_ws, size_t ws_size,
                              hipStream_t stream) {
    (void)in_sizes; (void)n_in; (void)out_size; (void)d_ws; (void)ws_size;
    const int*   s      = (const int*)d_in[0];
    const float* g      = (const float*)d_in[1];
    const float* W_emb  = (const float*)d_in[2];
    const float* b_emb  = (const float*)d_in[3];
    const float* W_g1   = (const float*)d_in[4];
    const float* b_g1   = (const float*)d_in[5];
    const float* W_g2   = (const float*)d_in[6];
    const float* b_g2   = (const float*)d_in[7];
    const float* W_gh   = (const float*)d_in[8];
    const float* b_gh   = (const float*)d_in[9];
    const float* W_gc   = (const float*)d_in[10];
    const float* b_gc   = (const float*)d_in[11];
    const float* Wi     = (const float*)d_in[12];
    const float* Wh     = (const float*)d_in[13];
    const float* b_lstm = (const float*)d_in[14];
    const float* W_amp  = (const float*)d_in[15];
    const float* b_amp  = (const float*)d_in[16];
    float* out = (float*)d_out;

    lstm_kernel<<<256, 256, 0, stream>>>(s, g, W_emb, b_emb, W_g1, b_g1, W_g2, b_g2,
                                         W_gh, b_gh, W_gc, b_gc, Wi, Wh, b_lstm,
                                         W_amp, b_amp, out);
}

// Round 2
// 258.800 us; speedup vs baseline: 1.0121x; 1.0121x over previous
//
#include <hip/hip_runtime.h>

// LSTM RNN: B=2048, L=256 (257 scan steps), F=64, H=32, K=2.
// R2: 512 wgs x 4 batch rows (2 wg/CU for latency hiding), A rows dup x4.
//   acc_init = C0 (Atv@B2 MFMA, precomputed) + s_bit * (B33-B32)  [f32 fma]
//   per-step MFMA chain depth 2: acc = mfma(a0,Wh0, mfma(a1,Wh1, acc_init))
//   logits = single diff column (W1-W0) -> softplus without shuffles,
//   round-robin over wave (t&3), executed AFTER the barrier.
// h exchange: 640B double buffer, b-stride 160B (<=2-way banks, 16B aligned).

typedef __attribute__((ext_vector_type(8))) short bf16x8;
typedef __attribute__((ext_vector_type(4))) float f32x4;

#define L2E 1.44269504088896340736f
#define LN2 0.69314718055994530942f

__device__ __forceinline__ short f2bf(float x) {
    unsigned u = __builtin_bit_cast(unsigned, x);
    unsigned r = (u + 0x7FFFu + ((u >> 16) & 1u)) >> 16;
    return (short)r;
}
__device__ __forceinline__ float fsig(float x) {
    float e = __builtin_amdgcn_exp2f(-L2E * x);
    return __builtin_amdgcn_rcpf(1.0f + e);
}
__device__ __forceinline__ float ftanh(float x) {
    float e = __builtin_amdgcn_exp2f(-2.0f * L2E * x);
    return 2.0f * __builtin_amdgcn_rcpf(1.0f + e) - 1.0f;
}

__global__ __launch_bounds__(256) void lstm_kernel(
    const int* __restrict__ s, const float* __restrict__ g,
    const float* __restrict__ W_emb, const float* __restrict__ b_emb,
    const float* __restrict__ W_g1, const float* __restrict__ b_g1,
    const float* __restrict__ W_g2, const float* __restrict__ b_g2,
    const float* __restrict__ W_gh, const float* __restrict__ b_gh,
    const float* __restrict__ W_gc, const float* __restrict__ b_gc,
    const float* __restrict__ Wi, const float* __restrict__ Wh,
    const float* __restrict__ b_lstm, const float* __restrict__ W_amp,
    const float* __restrict__ b_amp, float* __restrict__ out)
{
    __shared__ float Bx[35 * 256];              // 0-31: W_g2@Wi; 32-33: W_emb@Wi; 34: const
    __shared__ unsigned char sp_l[260];         // packed tokens: bit b of sp_l[t] = s_pad[b][t]
    __shared__ __align__(16) short Hb[2][320];  // h dbuf: [b(4) * 80 + f(64)] bf16
    __shared__ float red[4][4];                 // per-wave logp partials

    const int tid = threadIdx.x;
    const int w   = tid >> 6;     // wave 0..3
    const int l   = tid & 63;     // lane
    const int n2  = l & 15;       // MFMA col
    const int q   = l >> 4;       // MFMA k-quad
    const int wgb = blockIdx.x * 4;

    // ---------- Setup: folded B rows into LDS ----------
    {
        const int n = tid;
        float acc[35];
        #pragma unroll
        for (int i = 0; i < 35; ++i) acc[i] = 0.f;
        for (int f = 0; f < 64; ++f) {
            float wi = Wi[f * 256 + n];
            #pragma unroll
            for (int k = 0; k < 32; ++k) acc[k] += W_g2[k * 64 + f] * wi;  // uniform
            acc[32] += W_emb[f] * wi;
            acc[33] += W_emb[64 + f] * wi;
            acc[34] += (b_emb[f] + b_g2[f]) * wi;
        }
        acc[34] += b_lstm[n];
        #pragma unroll
        for (int i = 0; i < 35; ++i) Bx[i * 256 + n] = acc[i];
    }
    // token staging: sp_l[t+1] bits = s[:, t], sp_l[0] = 0
    {
        unsigned v = 0;
        #pragma unroll
        for (int b = 0; b < 4; ++b)
            v |= (unsigned)(s[(wgb + b) * 256 + tid] & 1) << b;
        sp_l[tid + 1] = (unsigned char)v;
        if (tid == 0) sp_l[0] = 0;
    }
    __syncthreads();

    // ---------- static fragments ----------
    bf16x8 Bf[4][2];          // Wh (K 0..63)
    float  c0add[4], Dsel[4]; // f32 one-hot/bias folds
    f32x4  C0[4];
    {
        bf16x8 B2f[4];
        #pragma unroll
        for (int gi = 0; gi < 4; ++gi) {
            const int n = gi * 64 + w * 16 + n2;
            #pragma unroll
            for (int kf = 0; kf < 2; ++kf)
                #pragma unroll
                for (int j = 0; j < 8; ++j)
                    Bf[gi][kf][j] = f2bf(Wh[(kf * 32 + q * 8 + j) * 256 + n]);
            #pragma unroll
            for (int j = 0; j < 8; ++j)
                B2f[gi][j] = f2bf(Bx[(q * 8 + j) * 256 + n]);
            c0add[gi] = Bx[32 * 256 + n] + Bx[34 * 256 + n];
            Dsel[gi]  = Bx[33 * 256 + n] - Bx[32 * 256 + n];
        }
        // Atv static A-frag (per-lane batch row ba = l&3)
        const float g_a = g[wgb + (l & 3)];
        bf16x8 Atv;
        #pragma unroll
        for (int j = 0; j < 8; ++j) {
            int k = q * 8 + j;
            Atv[j] = f2bf(tanhf(g_a * W_g1[k] + b_g1[k]));
        }
        const f32x4 zero4 = {0.f, 0.f, 0.f, 0.f};
        #pragma unroll
        for (int gi = 0; gi < 4; ++gi) {
            C0[gi] = __builtin_amdgcn_mfma_f32_16x16x32_bf16(Atv, B2f[gi], zero4, 0, 0, 0);
            #pragma unroll
            for (int r = 0; r < 4; ++r) C0[gi][r] += c0add[gi];
        }
    }
    // logit DIFF column frags (col 0 = W_amp[:,1]-W_amp[:,0]; others 0)
    bf16x8 BLd0, BLd1;
    f32x4 CL0;
    {
        #pragma unroll
        for (int j = 0; j < 8; ++j) {
            int k = q * 8 + j;
            BLd0[j] = (n2 == 0) ? f2bf(W_amp[k * 2 + 1] - W_amp[k * 2]) : (short)0;
            BLd1[j] = (n2 == 0) ? f2bf(W_amp[(k + 32) * 2 + 1] - W_amp[(k + 32) * 2]) : (short)0;
        }
        float bd = (n2 == 0) ? (b_amp[1] - b_amp[0]) : 0.f;
        CL0[0] = bd; CL0[1] = bd; CL0[2] = bd; CL0[3] = bd;
    }

    // ---------- state init ----------
    const int fcol  = w * 16 + n2;   // gate-phase f ownership
    const int bown  = l >> 4;        // gate-phase b ownership
    const int haddr = bown * 80 + fcol;
    float cst;
    {
        float gb = g[wgb + bown];
        cst = gb * W_gc[fcol] + b_gc[fcol];
        Hb[0][haddr] = f2bf(gb * W_gh[fcol] + b_gh[fcol]);
    }
    __syncthreads();

    // ---------- main recurrence ----------
    const int ra = (l & 3) * 80 + q * 8;   // A-frag read (shorts); 16B aligned
    const bool b4 = (l & 16) != 0, b5 = (l & 32) != 0;
    float slp[4] = {0.f, 0.f, 0.f, 0.f};
    unsigned spt = 0;                       // sp_l[0]

    for (int t = 0; t <= 256; ++t) {
        const int rb = t & 1;
        bf16x8 a0 = *(const bf16x8*)&Hb[rb][ra];
        bf16x8 a1 = *(const bf16x8*)&Hb[rb][ra + 32];
        unsigned spt_n = sp_l[t + 1];       // prefetch next token byte

        float fr0 = (float)(spt & 1), fr1 = (float)((spt >> 1) & 1);
        float fr2 = (float)((spt >> 2) & 1), fr3 = (float)((spt >> 3) & 1);

        f32x4 acc[4];
        #pragma unroll
        for (int gi = 0; gi < 4; ++gi) {
            f32x4 a = C0[gi];
            a[0] += fr0 * Dsel[gi]; a[1] += fr1 * Dsel[gi];
            a[2] += fr2 * Dsel[gi]; a[3] += fr3 * Dsel[gi];
            a = __builtin_amdgcn_mfma_f32_16x16x32_bf16(a1, Bf[gi][1], a, 0, 0, 0);
            acc[gi] = __builtin_amdgcn_mfma_f32_16x16x32_bf16(a0, Bf[gi][0], a, 0, 0, 0);
        }

        const bool rr = (t >= 1) && (w == (t & 3));
        f32x4 accL;
        if (rr) {
            f32x4 aL = __builtin_amdgcn_mfma_f32_16x16x32_bf16(a1, BLd1, CL0, 0, 0, 0);
            accL = __builtin_amdgcn_mfma_f32_16x16x32_bf16(a0, BLd0, aL, 0, 0, 0);
        }
        const unsigned spt_cur = spt;

        if (t < 256) {
            float z[4];
            #pragma unroll
            for (int gi = 0; gi < 4; ++gi) {
                float s01 = b4 ? acc[gi][1] : acc[gi][0];
                float s23 = b4 ? acc[gi][3] : acc[gi][2];
                z[gi] = b5 ? s23 : s01;
            }
            float si = fsig(z[0]), sf = fsig(z[1]), tg = ftanh(z[2]), so = fsig(z[3]);
            float c = sf * cst + si * tg;
            cst = c;
            float h = so * ftanh(c);
            Hb[1 - rb][haddr] = f2bf(h);
        }
        spt = spt_n;
        __syncthreads();

        if (rr) {   // post-barrier: overlaps other waves' next-step MFMAs
            #pragma unroll
            for (int r = 0; r < 4; ++r) {
                float d = accL[r];
                float x = ((spt_cur >> r) & 1u) ? -d : d;     // l_other - l_s
                float e = __builtin_amdgcn_exp2f(L2E * x);
                slp[r] -= LN2 * __builtin_amdgcn_logf(1.0f + e);
            }
        }
    }

    // ---------- epilogue ----------
    if (l == 0) {
        #pragma unroll
        for (int r = 0; r < 4; ++r) red[w][r] = slp[r];
    }
    __syncthreads();
    if (tid < 4)
        out[wgb + tid] = red[0][tid] + red[1][tid] + red[2][tid] + red[3][tid];
}

extern "C" void kernel_launch(void* const* d_in, const int* in_sizes, int n_in,
                              void* d_out, int out_size, void* d_ws, size_t ws_size,
                              hipStream_t stream) {
    (void)in_sizes; (void)n_in; (void)out_size; (void)d_ws; (void)ws_size;
    const int*   s      = (const int*)d_in[0];
    const float* g      = (const float*)d_in[1];
    const float* W_emb  = (const float*)d_in[2];
    const float* b_emb  = (const float*)d_in[3];
    const float* W_g1   = (const float*)d_in[4];
    const float* b_g1   = (const float*)d_in[5];
    const float* W_g2   = (const float*)d_in[6];
    const float* b_g2   = (const float*)d_in[7];
    const float* W_gh   = (const float*)d_in[8];
    const float* b_gh   = (const float*)d_in[9];
    const float* W_gc   = (const float*)d_in[10];
    const float* b_gc   = (const float*)d_in[11];
    const float* Wi     = (const float*)d_in[12];
    const float* Wh     = (const float*)d_in[13];
    const float* b_lstm = (const float*)d_in[14];
    const float* W_amp  = (const float*)d_in[15];
    const float* b_amp  = (const float*)d_in[16];
    float* out = (float*)d_out;

    lstm_kernel<<<512, 256, 0, stream>>>(s, g, W_emb, b_emb, W_g1, b_g1, W_g2, b_g2,
                                         W_gh, b_gh, W_gc, b_gc, Wi, Wh, b_lstm,
                                         W_amp, b_amp, out);
}